// Round 4
// baseline (1726.190 us; speedup 1.0000x reference)
//
#include <hip/hip_runtime.h>

// Problem constants (fixed by setup_inputs: B=16, H=W=1024, k=9 -> R=4)
#define HH 1024
#define WW 1024
#define BB 16
#define ROWS 32              // output rows per block (2048 blocks = 8/CU)
#define DMAXC 15.0f
#define ENHC 2.0f
#define NEGWC 1.5f
#define EGFC 10.0f

__device__ __forceinline__ float lossterm(float p, float s) {
    float sd = (s > 0.f) ? DMAXC : s;
    sd = (sd < 0.f) ? sd * ENHC : sd;
    float w = (sd < 0.f) ? (1.f + NEGWC) : 1.f;
    float d = p - sd;
    return d * d * w;
}

// pin a wave-uniform float into an SGPR
__device__ __forceinline__ float rfl(float x) {
    return __uint_as_float(__builtin_amdgcn_readfirstlane(__float_as_uint(x)));
}

// One input row: stage 72-float window into wave-private LDS (lane<18 does a
// float4 load+store), horizontal 9-tap conv into register ring slot SLOT,
// fused loss on loss rows.
// The lgkmcnt(0)+memory-clobber fence between ds_write and ds_read is
// CORRECTNESS-REQUIRED: lanes >=18 read data written by lanes 0..17, so the
// reads have no within-thread dependence on the write and the compiler may
// otherwise reorder them (round-3 failure: absmax 52.7 without the fence).
#define HROW(SLOT, J, DOLOSS)                                                 \
    {                                                                         \
        const int yin_ = r0 - 4 + (J);                                        \
        if (lane < 18) {                                                      \
            const int gc_ = c0 - 4 + 4 * lane;                                \
            float4 v4_ = make_float4(0.f, 0.f, 0.f, 0.f);                     \
            if ((unsigned)yin_ < HH && (unsigned)gc_ < WW)                    \
                v4_ = *(const float4*)&img[(size_t)yin_ * WW + gc_];          \
            *(float4*)&s_row[wid][4 * lane] = v4_;                            \
        }                                                                     \
        asm volatile("s_waitcnt lgkmcnt(0)" ::: "memory");                    \
        float sv_ = 0.f;                                                      \
        if (DOLOSS) sv_ = snk[(size_t)yin_ * WW + c0 + lane];                 \
        float hg_ = 0.f, hd_ = 0.f, ag_ = 0.f, ad_ = 0.f, pv_ = 0.f;          \
        _Pragma("unroll")                                                     \
        for (int k_ = 0; k_ < 9; ++k_) {                                      \
            float v_ = s_row[wid][lane + k_];                                 \
            if (k_ == 4) pv_ = v_;                                            \
            float a_ = fabsf(v_); /* abs input modifier: free */              \
            hg_ += g[k_] * v_;                                                \
            hd_ += dg[k_] * v_;                                               \
            ag_ += g[k_] * a_;                                                \
            ad_ += dg[k_] * a_;                                               \
        }                                                                     \
        hgP[SLOT] = hg_; hdP[SLOT] = hd_;                                     \
        hgA[SLOT] = ag_; hdA[SLOT] = ad_;                                     \
        if (DOLOSS) lsum += lossterm(pv_, sv_);                               \
    }

// One output row from the ring window starting at compile-time slot BASE:
// vertical 9-tap (EGFC pre-folded into dgE/gE), 4 coalesced dword stores
// (64 consecutive floats per wave per image; the out+1 misalignment only
// splits a cacheline -> measured 1.25x write amplification, accepted).
#define EMIT(YO, BASE)                                                        \
    {                                                                         \
        float c0_ = 0.f, c1_ = 0.f, w0_ = 0.f, w1_ = 0.f;                     \
        _Pragma("unroll")                                                     \
        for (int i_ = 0; i_ < 9; ++i_) {                                      \
            const int s_ = ((BASE) + i_) % 9; /* compile-time */              \
            c0_ += dgE[i_] * hgP[s_];                                         \
            c1_ += gE[i_] * hdP[s_];                                          \
            w0_ += dgE[i_] * hgA[s_];                                         \
            w1_ += gE[i_] * hdA[s_];                                          \
        }                                                                     \
        const size_t o_ = (size_t)(YO) * WW + c0 + lane;                      \
        g0[o_] = c0_;                                                         \
        g1[o_] = c1_;                                                         \
        g0W[o_] = w0_;                                                        \
        g1W[o_] = w1_;                                                        \
    }

__global__ __launch_bounds__(256, 8) void snake_rows(
    const float* __restrict__ pred, const float* __restrict__ snake,
    const float* __restrict__ fltr, float* __restrict__ out)
{
    __shared__ float s_row[4][72];   // per-wave private row window (halo 4+4)
    __shared__ float s_red[4];

    const int t = threadIdx.x;
    const int lane = t & 63;
    const int wid = t >> 6;
    const int b = blockIdx.z;
    const int r0 = blockIdx.y * ROWS;
    const int c0 = blockIdx.x * 256 + wid * 64;   // this wave's 64-col strip

    // --- separable filter recovery: dg'[i]=row-sum of f_dy (=dg[i]*sum(g)),
    // g'[j]=f_dy[0][j]/dg'[0] (=g[j]/sum(g)); the sum(g) factors cancel.
    float g[9], dg[9], gE[9], dgE[9];
#pragma unroll
    for (int i = 0; i < 9; ++i) {
        float s = 0.f;
#pragma unroll
        for (int j = 0; j < 9; ++j) s += fltr[i * 9 + j];
        dg[i] = rfl(s);
        dgE[i] = rfl(EGFC * s);
    }
    {
        float inv = 1.f / dg[0];
#pragma unroll
        for (int j = 0; j < 9; ++j) {
            g[j] = rfl(fltr[j] * inv);
            gE[j] = rfl(EGFC * g[j]);
        }
    }

    const float* img = pred + (size_t)b * (HH * WW);
    const float* snk = snake + (size_t)b * (HH * WW);
    float* g0 = out + 1 + ((size_t)(b * 2 + 0)) * (HH * WW);
    float* g1 = out + 1 + ((size_t)(b * 2 + 1)) * (HH * WW);
    float* g0W = g0 + (size_t)BB * 2 * HH * WW;
    float* g1W = g1 + (size_t)BB * 2 * HH * WW;

    // 9-deep register rings of horizontal-conv rows (statically indexed)
    float hgP[9], hdP[9], hgA[9], hdA[9];
    float lsum = 0.f;

    // ---- warmup: input rows j=0..8 (r0-4 .. r0+4); first output after j=8
#pragma unroll
    for (int u = 0; u < 9; ++u) { HROW(u, u, (u >= 4)); }
    EMIT(r0, 0);

    // ---- main: 3 chunks x 9 rows (j = 9..35, all loss rows) ----
#pragma unroll 1
    for (int m = 0; m < 3; ++m) {
        const int jb = 9 + 9 * m;
#pragma unroll
        for (int u = 0; u < 9; ++u) {
            HROW(u, jb + u, true);
            EMIT(r0 + jb + u - 8, (u + 1) % 9);
        }
    }

    // ---- tail: j = 36..39 (below-band halo rows, no loss) ----
#pragma unroll
    for (int u = 0; u < 4; ++u) {
        HROW(u, 36 + u, false);
        EMIT(r0 + 28 + u, (u + 1) % 9);
    }

    // --- block reduction -> one atomicAdd per block
#pragma unroll
    for (int off = 32; off > 0; off >>= 1) lsum += __shfl_down(lsum, off);
    if (lane == 0) s_red[wid] = lsum;
    __syncthreads();
    if (t == 0) {
        float tot = s_red[0] + s_red[1] + s_red[2] + s_red[3];
        atomicAdd(out, tot * (1.0f / 16777216.0f));  // /(B*H*W), exact pow2
    }
}

extern "C" void kernel_launch(void* const* d_in, const int* in_sizes, int n_in,
                              void* d_out, int out_size, void* d_ws, size_t ws_size,
                              hipStream_t stream) {
    const float* pred = (const float*)d_in[0];
    const float* snake = (const float*)d_in[1];
    const float* fltr = (const float*)d_in[2];
    float* out = (float*)d_out;

    // loss accumulator must start at 0 (d_out is poisoned before every launch)
    hipMemsetAsync(out, 0, sizeof(float), stream);

    dim3 grid(WW / 256, HH / ROWS, BB);   // (4, 32, 16) = 2048 blocks
    snake_rows<<<grid, 256, 0, stream>>>(pred, snake, fltr, out);
}

// Round 5
// 414.479 us; speedup vs baseline: 4.1647x; 4.1647x over previous
//
#include <hip/hip_runtime.h>

// Problem constants (fixed by setup_inputs: B=16, H=W=1024, k=9 -> R=4)
#define HH 1024
#define WW 1024
#define BB 16
#define ROWS 32              // output rows per block (2048 blocks = 8/CU)
#define DMAXC 15.0f
#define ENHC 2.0f
#define NEGWC 1.5f
#define EGFC 10.0f

__device__ __forceinline__ float lossterm(float p, float s) {
    float sd = (s > 0.f) ? DMAXC : s;
    sd = (sd < 0.f) ? sd * ENHC : sd;
    float w = (sd < 0.f) ? (1.f + NEGWC) : 1.f;
    float d = p - sd;
    return d * d * w;
}

// pin a wave-uniform float into an SGPR
__device__ __forceinline__ float rfl(float x) {
    return __uint_as_float(__builtin_amdgcn_readfirstlane(__float_as_uint(x)));
}

// One input row: stage 72-float window into wave-private LDS (lane<18 does a
// float4 load+store), horizontal 9-tap conv into register ring slot SLOT,
// fused loss on loss rows.
// The lgkmcnt(0)+memory-clobber fence between ds_write and ds_read is
// CORRECTNESS-REQUIRED: lanes >=18 read data written by lanes 0..17, so the
// reads have no within-thread dependence on the write and the compiler may
// otherwise reorder them (round-3 failure: absmax 52.7 without the fence).
#define HROW(SLOT, J, DOLOSS)                                                 \
    {                                                                         \
        const int yin_ = r0 - 4 + (J);                                        \
        if (lane < 18) {                                                      \
            const int gc_ = c0 - 4 + 4 * lane;                                \
            float4 v4_ = make_float4(0.f, 0.f, 0.f, 0.f);                     \
            if ((unsigned)yin_ < HH && (unsigned)gc_ < WW)                    \
                v4_ = *(const float4*)&img[(size_t)yin_ * WW + gc_];          \
            *(float4*)&s_row[wid][4 * lane] = v4_;                            \
        }                                                                     \
        asm volatile("s_waitcnt lgkmcnt(0)" ::: "memory");                    \
        float sv_ = 0.f;                                                      \
        if (DOLOSS) sv_ = snk[(size_t)yin_ * WW + c0 + lane];                 \
        float hg_ = 0.f, hd_ = 0.f, ag_ = 0.f, ad_ = 0.f, pv_ = 0.f;          \
        _Pragma("unroll")                                                     \
        for (int k_ = 0; k_ < 9; ++k_) {                                      \
            float v_ = s_row[wid][lane + k_];                                 \
            if (k_ == 4) pv_ = v_;                                            \
            float a_ = fabsf(v_); /* abs input modifier: free */              \
            hg_ += g[k_] * v_;                                                \
            hd_ += dg[k_] * v_;                                               \
            ag_ += g[k_] * a_;                                                \
            ad_ += dg[k_] * a_;                                               \
        }                                                                     \
        hgP[SLOT] = hg_; hdP[SLOT] = hd_;                                     \
        hgA[SLOT] = ag_; hdA[SLOT] = ad_;                                     \
        if (DOLOSS) lsum += lossterm(pv_, sv_);                               \
    }

// One output row from the ring window starting at compile-time slot BASE:
// vertical 9-tap (EGFC pre-folded into dgE/gE), 4 coalesced dword stores
// (64 consecutive floats per wave per image; the out+1 misalignment only
// splits a cacheline -> measured 1.25x write amplification, accepted).
#define EMIT(YO, BASE)                                                        \
    {                                                                         \
        float c0_ = 0.f, c1_ = 0.f, w0_ = 0.f, w1_ = 0.f;                     \
        _Pragma("unroll")                                                     \
        for (int i_ = 0; i_ < 9; ++i_) {                                      \
            const int s_ = ((BASE) + i_) % 9; /* compile-time */              \
            c0_ += dgE[i_] * hgP[s_];                                         \
            c1_ += gE[i_] * hdP[s_];                                          \
            w0_ += dgE[i_] * hgA[s_];                                         \
            w1_ += gE[i_] * hdA[s_];                                          \
        }                                                                     \
        const size_t o_ = (size_t)(YO) * WW + c0 + lane;                      \
        g0[o_] = c0_;                                                         \
        g1[o_] = c1_;                                                         \
        g0W[o_] = w0_;                                                        \
        g1W[o_] = w1_;                                                        \
    }

// NOTE: no min-waves arg! Round 4's __launch_bounds__(256, 8) forced the
// allocator to 32 VGPR -> ring arrays spilled to scratch -> 3.8 GB of HBM
// scratch traffic, 7x slowdown. The kernel naturally allocates ~64 VGPR,
// which already permits 8 waves/SIMD (512/64); the ROWS=32 grid supplies
// 8 blocks/CU. Let the allocator breathe.
__global__ __launch_bounds__(256) void snake_rows(
    const float* __restrict__ pred, const float* __restrict__ snake,
    const float* __restrict__ fltr, float* __restrict__ out)
{
    __shared__ float s_row[4][72];   // per-wave private row window (halo 4+4)
    __shared__ float s_red[4];

    const int t = threadIdx.x;
    const int lane = t & 63;
    const int wid = t >> 6;
    const int b = blockIdx.z;
    const int r0 = blockIdx.y * ROWS;
    const int c0 = blockIdx.x * 256 + wid * 64;   // this wave's 64-col strip

    // --- separable filter recovery: dg'[i]=row-sum of f_dy (=dg[i]*sum(g)),
    // g'[j]=f_dy[0][j]/dg'[0] (=g[j]/sum(g)); the sum(g) factors cancel.
    // All coefficients SGPR-pinned via rfl() -> no VGPR cost.
    float g[9], dg[9], gE[9], dgE[9];
#pragma unroll
    for (int i = 0; i < 9; ++i) {
        float s = 0.f;
#pragma unroll
        for (int j = 0; j < 9; ++j) s += fltr[i * 9 + j];
        dg[i] = rfl(s);
        dgE[i] = rfl(EGFC * s);
    }
    {
        float inv = 1.f / dg[0];
#pragma unroll
        for (int j = 0; j < 9; ++j) {
            g[j] = rfl(fltr[j] * inv);
            gE[j] = rfl(EGFC * g[j]);
        }
    }

    const float* img = pred + (size_t)b * (HH * WW);
    const float* snk = snake + (size_t)b * (HH * WW);
    float* g0 = out + 1 + ((size_t)(b * 2 + 0)) * (HH * WW);
    float* g1 = out + 1 + ((size_t)(b * 2 + 1)) * (HH * WW);
    float* g0W = g0 + (size_t)BB * 2 * HH * WW;
    float* g1W = g1 + (size_t)BB * 2 * HH * WW;

    // 9-deep register rings of horizontal-conv rows (statically indexed)
    float hgP[9], hdP[9], hgA[9], hdA[9];
    float lsum = 0.f;

    // ---- warmup: input rows j=0..8 (r0-4 .. r0+4); first output after j=8
#pragma unroll
    for (int u = 0; u < 9; ++u) { HROW(u, u, (u >= 4)); }
    EMIT(r0, 0);

    // ---- main: 3 chunks x 9 rows (j = 9..35, all loss rows) ----
#pragma unroll 1
    for (int m = 0; m < 3; ++m) {
        const int jb = 9 + 9 * m;
#pragma unroll
        for (int u = 0; u < 9; ++u) {
            HROW(u, jb + u, true);
            EMIT(r0 + jb + u - 8, (u + 1) % 9);
        }
    }

    // ---- tail: j = 36..39 (below-band halo rows, no loss) ----
#pragma unroll
    for (int u = 0; u < 4; ++u) {
        HROW(u, 36 + u, false);
        EMIT(r0 + 28 + u, (u + 1) % 9);
    }

    // --- block reduction -> one atomicAdd per block
#pragma unroll
    for (int off = 32; off > 0; off >>= 1) lsum += __shfl_down(lsum, off);
    if (lane == 0) s_red[wid] = lsum;
    __syncthreads();
    if (t == 0) {
        float tot = s_red[0] + s_red[1] + s_red[2] + s_red[3];
        atomicAdd(out, tot * (1.0f / 16777216.0f));  // /(B*H*W), exact pow2
    }
}

extern "C" void kernel_launch(void* const* d_in, const int* in_sizes, int n_in,
                              void* d_out, int out_size, void* d_ws, size_t ws_size,
                              hipStream_t stream) {
    const float* pred = (const float*)d_in[0];
    const float* snake = (const float*)d_in[1];
    const float* fltr = (const float*)d_in[2];
    float* out = (float*)d_out;

    // loss accumulator must start at 0 (d_out is poisoned before every launch)
    hipMemsetAsync(out, 0, sizeof(float), stream);

    dim3 grid(WW / 256, HH / ROWS, BB);   // (4, 32, 16) = 2048 blocks
    snake_rows<<<grid, 256, 0, stream>>>(pred, snake, fltr, out);
}

// Round 6
// 406.755 us; speedup vs baseline: 4.2438x; 1.0190x over previous
//
#include <hip/hip_runtime.h>

// Problem constants (fixed by setup_inputs: B=16, H=W=1024, k=9 -> R=4)
#define HH 1024
#define WW 1024
#define BB 16
#define ROWS 32              // output rows per block (2048 blocks = 8/CU)
#define DMAXC 15.0f
#define ENHC 2.0f
#define NEGWC 1.5f
#define EGFC 10.0f

__device__ __forceinline__ float lossterm(float p, float s) {
    float sd = (s > 0.f) ? DMAXC : s;
    sd = (sd < 0.f) ? sd * ENHC : sd;
    float w = (sd < 0.f) ? (1.f + NEGWC) : 1.f;
    float d = p - sd;
    return d * d * w;
}

// pin a wave-uniform float into an SGPR
__device__ __forceinline__ float rfl(float x) {
    return __uint_as_float(__builtin_amdgcn_readfirstlane(__float_as_uint(x)));
}

// ---- stage NR (<=9) input rows [JB .. JB+NR) of this wave's 72-wide window
// into the per-wave LDS chunk buffer. Lanes 0..53 each carry one float4 per
// sub-step: row = 3q + lane/18, pos = lane%18. All loads are independent ->
// single batched latency exposure per chunk (the round-5 kernel paid it per
// row: load -> vmcnt(0) -> ds_write every row was the structural stall).
#define STAGE(JB, NR)                                                         \
    {                                                                         \
        _Pragma("unroll")                                                     \
        for (int q_ = 0; q_ < ((NR) + 2) / 3; ++q_) {                         \
            const int row_ = 3 * q_ + lrow;                                   \
            if (lane < 54 && row_ < (NR)) {                                   \
                const int yin_ = r0 - 4 + (JB) + row_;                        \
                const int gc_ = c0 - 4 + 4 * lpos;                            \
                float4 v4_ = make_float4(0.f, 0.f, 0.f, 0.f);                 \
                if ((unsigned)yin_ < HH && (unsigned)gc_ < WW)                \
                    v4_ = *(const float4*)&img[(size_t)yin_ * WW + gc_];      \
                *(float4*)&s_ch[wid][row_][4 * lpos] = v4_;                   \
            }                                                                 \
        }                                                                     \
        /* CORRECTNESS-REQUIRED (round-3 failure): lanes >=18*3 read data */  \
        /* written by other lanes; no within-thread dep -> must fence.    */  \
        asm volatile("s_waitcnt lgkmcnt(0)" ::: "memory");                    \
    }

// ---- consume one staged row U (input row J = chunk base + U): horizontal
// 9-tap conv into register ring slot SLOT, fused loss on loss rows.
// Reads are consecutive-lane (2-way bank alias = free).
#define CROW(SLOT, U, J, DOLOSS)                                              \
    {                                                                         \
        float sv_ = 0.f;                                                      \
        if (DOLOSS) {                                                         \
            const int yin_ = r0 - 4 + (J);                                    \
            sv_ = snk[(size_t)yin_ * WW + c0 + lane];                         \
        }                                                                     \
        float hg_ = 0.f, hd_ = 0.f, ag_ = 0.f, ad_ = 0.f, pv_ = 0.f;          \
        _Pragma("unroll")                                                     \
        for (int k_ = 0; k_ < 9; ++k_) {                                      \
            float v_ = s_ch[wid][U][lane + k_];                               \
            if (k_ == 4) pv_ = v_;                                            \
            float a_ = fabsf(v_); /* abs input modifier: free */              \
            hg_ += g[k_] * v_;                                                \
            hd_ += dg[k_] * v_;                                               \
            ag_ += g[k_] * a_;                                                \
            ad_ += dg[k_] * a_;                                               \
        }                                                                     \
        hgP[SLOT] = hg_; hdP[SLOT] = hd_;                                     \
        hgA[SLOT] = ag_; hdA[SLOT] = ad_;                                     \
        if (DOLOSS) lsum += lossterm(pv_, sv_);                               \
    }

// One output row from the ring window starting at compile-time slot BASE:
// vertical 9-tap (EGFC pre-folded into dgE/gE), 4 coalesced dword stores
// (64 consecutive floats per wave per image; the out+1 misalignment only
// splits a cacheline -> measured 1.25x write amplification, accepted).
#define EMIT(YO, BASE)                                                        \
    {                                                                         \
        float c0_ = 0.f, c1_ = 0.f, w0_ = 0.f, w1_ = 0.f;                     \
        _Pragma("unroll")                                                     \
        for (int i_ = 0; i_ < 9; ++i_) {                                      \
            const int s_ = ((BASE) + i_) % 9; /* compile-time */              \
            c0_ += dgE[i_] * hgP[s_];                                         \
            c1_ += gE[i_] * hdP[s_];                                          \
            w0_ += dgE[i_] * hgA[s_];                                         \
            w1_ += gE[i_] * hdA[s_];                                          \
        }                                                                     \
        const size_t o_ = (size_t)(YO) * WW + c0 + lane;                      \
        g0[o_] = c0_;                                                         \
        g1[o_] = c1_;                                                         \
        g0W[o_] = w0_;                                                        \
        g1W[o_] = w1_;                                                        \
    }

// NOTE: no min-waves arg (round 4: __launch_bounds__(256,8) forced 32 VGPR
// -> ring spill -> 3.8 GB scratch traffic, 7x slowdown). Let the allocator
// breathe; the ROWS=32 grid supplies 8 blocks/CU.
__global__ __launch_bounds__(256) void snake_rows(
    const float* __restrict__ pred, const float* __restrict__ snake,
    const float* __restrict__ fltr, float* __restrict__ out)
{
    __shared__ float s_ch[4][9][72];   // per-wave 9-row staged chunk (10.1 KB)
    __shared__ float s_red[4];

    const int t = threadIdx.x;
    const int lane = t & 63;
    const int wid = t >> 6;
    const int lrow = lane / 18;        // 0..2 for staging lanes (<54)
    const int lpos = lane - 18 * lrow; // 0..17
    const int b = blockIdx.z;
    const int r0 = blockIdx.y * ROWS;
    const int c0 = blockIdx.x * 256 + wid * 64;   // this wave's 64-col strip

    // --- separable filter recovery: dg'[i]=row-sum of f_dy (=dg[i]*sum(g)),
    // g'[j]=f_dy[0][j]/dg'[0] (=g[j]/sum(g)); the sum(g) factors cancel.
    // All coefficients SGPR-pinned via rfl() -> no VGPR cost.
    float g[9], dg[9], gE[9], dgE[9];
#pragma unroll
    for (int i = 0; i < 9; ++i) {
        float s = 0.f;
#pragma unroll
        for (int j = 0; j < 9; ++j) s += fltr[i * 9 + j];
        dg[i] = rfl(s);
        dgE[i] = rfl(EGFC * s);
    }
    {
        float inv = 1.f / dg[0];
#pragma unroll
        for (int j = 0; j < 9; ++j) {
            g[j] = rfl(fltr[j] * inv);
            gE[j] = rfl(EGFC * g[j]);
        }
    }

    const float* img = pred + (size_t)b * (HH * WW);
    const float* snk = snake + (size_t)b * (HH * WW);
    float* g0 = out + 1 + ((size_t)(b * 2 + 0)) * (HH * WW);
    float* g1 = out + 1 + ((size_t)(b * 2 + 1)) * (HH * WW);
    float* g0W = g0 + (size_t)BB * 2 * HH * WW;
    float* g1W = g1 + (size_t)BB * 2 * HH * WW;

    // 9-deep register rings of horizontal-conv rows (statically indexed)
    float hgP[9], hdP[9], hgA[9], hdA[9];
    float lsum = 0.f;

    // ---- warmup chunk: input rows j=0..8 (r0-4 .. r0+4) ----
    STAGE(0, 9);
#pragma unroll
    for (int u = 0; u < 9; ++u) { CROW(u, u, u, (u >= 4)); }
    EMIT(r0, 0);
    asm volatile("" ::: "memory");  // pin consume-reads before next stage-writes

    // ---- main: 3 chunks x 9 rows (j = 9..35, all loss rows) ----
#pragma unroll 1
    for (int m = 0; m < 3; ++m) {
        const int jb = 9 + 9 * m;
        STAGE(jb, 9);
#pragma unroll
        for (int u = 0; u < 9; ++u) {
            CROW(u, u, jb + u, true);
            EMIT(r0 + jb + u - 8, (u + 1) % 9);
        }
        asm volatile("" ::: "memory");
    }

    // ---- tail chunk: j = 36..39 (below-band halo rows, no loss) ----
    STAGE(36, 4);
#pragma unroll
    for (int u = 0; u < 4; ++u) {
        CROW(u, u, 36 + u, false);
        EMIT(r0 + 28 + u, (u + 1) % 9);
    }

    // --- block reduction -> one atomicAdd per block
#pragma unroll
    for (int off = 32; off > 0; off >>= 1) lsum += __shfl_down(lsum, off);
    if (lane == 0) s_red[wid] = lsum;
    __syncthreads();
    if (t == 0) {
        float tot = s_red[0] + s_red[1] + s_red[2] + s_red[3];
        atomicAdd(out, tot * (1.0f / 16777216.0f));  // /(B*H*W), exact pow2
    }
}

extern "C" void kernel_launch(void* const* d_in, const int* in_sizes, int n_in,
                              void* d_out, int out_size, void* d_ws, size_t ws_size,
                              hipStream_t stream) {
    const float* pred = (const float*)d_in[0];
    const float* snake = (const float*)d_in[1];
    const float* fltr = (const float*)d_in[2];
    float* out = (float*)d_out;

    // loss accumulator must start at 0 (d_out is poisoned before every launch)
    hipMemsetAsync(out, 0, sizeof(float), stream);

    dim3 grid(WW / 256, HH / ROWS, BB);   // (4, 32, 16) = 2048 blocks
    snake_rows<<<grid, 256, 0, stream>>>(pred, snake, fltr, out);
}

// Round 7
// 390.011 us; speedup vs baseline: 4.4260x; 1.0429x over previous
//
#include <hip/hip_runtime.h>

// Problem constants (fixed by setup_inputs: B=16, H=W=1024, k=9 -> R=4)
#define HH 1024
#define WW 1024
#define BB 16
#define ROWS 32              // output rows per block (2048 blocks = 8/CU)
#define DMAXC 15.0f
#define ENHC 2.0f
#define NEGWC 1.5f
#define EGFC 10.0f

__device__ __forceinline__ float lossterm(float p, float s) {
    float sd = (s > 0.f) ? DMAXC : s;
    sd = (sd < 0.f) ? sd * ENHC : sd;
    float w = (sd < 0.f) ? (1.f + NEGWC) : 1.f;
    float d = p - sd;
    return d * d * w;
}

// pin a wave-uniform float into an SGPR
__device__ __forceinline__ float rfl(float x) {
    return __uint_as_float(__builtin_amdgcn_readfirstlane(__float_as_uint(x)));
}

// ---- T14 issue-early: preload NR (<=9) rows [JB..JB+NR) of this wave's
// 72-wide window into registers pA/pB/pC. Lanes 0..53: row = 3q + lane/18,
// pos = lane%18. Issued BEFORE the current chunk's consume so the ~900cy
// HBM latency hides under ~2k cycles of compute (round-6 paid it serially:
// loads were issued after the previous consume finished).
#define PRELOAD(JB, NR)                                                       \
    {                                                                         \
        pA = pB = pC = make_float4(0.f, 0.f, 0.f, 0.f);                       \
        const int gc_ = c0 - 4 + 4 * lpos;                                    \
        if (lane < 54 && (unsigned)gc_ < WW) {                                \
            const int y0_ = r0 - 4 + (JB) + lrow;                             \
            if (lrow < (NR) && (unsigned)y0_ < HH)                            \
                pA = *(const float4*)&img[(size_t)y0_ * WW + gc_];            \
            if (3 + lrow < (NR) && (unsigned)(y0_ + 3) < HH)                  \
                pB = *(const float4*)&img[(size_t)(y0_ + 3) * WW + gc_];      \
            if (6 + lrow < (NR) && (unsigned)(y0_ + 6) < HH)                  \
                pC = *(const float4*)&img[(size_t)(y0_ + 6) * WW + gc_];      \
        }                                                                     \
    }

// ---- write-late: dump the preloaded registers into the wave-private LDS
// chunk buffer. The vmcnt wait on pA/pB/pC is free by now. Fence after the
// writes is CORRECTNESS-REQUIRED (round-3 failure: lanes read other lanes'
// writes with no within-thread dependence -> compiler may reorder).
#define WRITECHUNK(NR)                                                        \
    {                                                                         \
        if (lane < 54) {                                                      \
            if (lrow < (NR))     *(float4*)&s_ch[wid][lrow][4 * lpos] = pA;   \
            if (3 + lrow < (NR)) *(float4*)&s_ch[wid][3 + lrow][4 * lpos] = pB;\
            if (6 + lrow < (NR)) *(float4*)&s_ch[wid][6 + lrow][4 * lpos] = pC;\
        }                                                                     \
        asm volatile("s_waitcnt lgkmcnt(0)" ::: "memory");                    \
    }

// ---- consume one staged row U: horizontal 9-tap conv into register ring
// slot SLOT (compile-time), fused loss from the pre-batched svv[U].
// LDS reads are consecutive-lane (2-way bank alias = free).
#define CROW(SLOT, U, DOLOSS)                                                 \
    {                                                                         \
        float hg_ = 0.f, hd_ = 0.f, ag_ = 0.f, ad_ = 0.f, pv_ = 0.f;          \
        _Pragma("unroll")                                                     \
        for (int k_ = 0; k_ < 9; ++k_) {                                      \
            float v_ = s_ch[wid][U][lane + k_];                               \
            if (k_ == 4) pv_ = v_;                                            \
            float a_ = fabsf(v_); /* abs input modifier: free */              \
            hg_ += g[k_] * v_;                                                \
            hd_ += dg[k_] * v_;                                               \
            ag_ += g[k_] * a_;                                                \
            ad_ += dg[k_] * a_;                                               \
        }                                                                     \
        hgP[SLOT] = hg_; hdP[SLOT] = hd_;                                     \
        hgA[SLOT] = ag_; hdA[SLOT] = ad_;                                     \
        if (DOLOSS) lsum += lossterm(pv_, svv[U]);                            \
    }

// One output row from the ring window starting at compile-time slot BASE:
// vertical 9-tap (EGFC pre-folded into dgE/gE), 4 coalesced dword stores
// (64 consecutive floats per wave per image; the out+1 misalignment only
// splits a cacheline -> measured 1.25x write amplification, accepted).
#define EMIT(YO, BASE)                                                        \
    {                                                                         \
        float c0_ = 0.f, c1_ = 0.f, w0_ = 0.f, w1_ = 0.f;                     \
        _Pragma("unroll")                                                     \
        for (int i_ = 0; i_ < 9; ++i_) {                                      \
            const int s_ = ((BASE) + i_) % 9; /* compile-time */              \
            c0_ += dgE[i_] * hgP[s_];                                         \
            c1_ += gE[i_] * hdP[s_];                                          \
            w0_ += dgE[i_] * hgA[s_];                                         \
            w1_ += gE[i_] * hdA[s_];                                          \
        }                                                                     \
        const size_t o_ = (size_t)(YO) * WW + c0 + lane;                      \
        g0[o_] = c0_;                                                         \
        g1[o_] = c1_;                                                         \
        g0W[o_] = w0_;                                                        \
        g1W[o_] = w1_;                                                        \
    }

// NOTE: no min-waves arg (round 4: __launch_bounds__(256,8) forced 32 VGPR
// -> ring spill -> 3.8 GB scratch traffic, 7x slowdown). Let the allocator
// breathe; the ROWS=32 grid supplies 8 blocks/CU.
__global__ __launch_bounds__(256) void snake_rows(
    const float* __restrict__ pred, const float* __restrict__ snake,
    const float* __restrict__ fltr, float* __restrict__ out)
{
    __shared__ float s_ch[4][9][72];   // per-wave 9-row staged chunk (10.1 KB)
    __shared__ float s_red[4];

    const int t = threadIdx.x;
    const int lane = t & 63;
    const int wid = t >> 6;
    const int lrow = lane / 18;        // 0..2 for staging lanes (<54)
    const int lpos = lane - 18 * lrow; // 0..17
    const int b = blockIdx.z;
    const int r0 = blockIdx.y * ROWS;
    const int c0 = blockIdx.x * 256 + wid * 64;   // this wave's 64-col strip

    // --- separable filter recovery: dg'[i]=row-sum of f_dy (=dg[i]*sum(g)),
    // g'[j]=f_dy[0][j]/dg'[0] (=g[j]/sum(g)); the sum(g) factors cancel.
    // All coefficients SGPR-pinned via rfl() -> no VGPR cost.
    float g[9], dg[9], gE[9], dgE[9];
#pragma unroll
    for (int i = 0; i < 9; ++i) {
        float s = 0.f;
#pragma unroll
        for (int j = 0; j < 9; ++j) s += fltr[i * 9 + j];
        dg[i] = rfl(s);
        dgE[i] = rfl(EGFC * s);
    }
    {
        float inv = 1.f / dg[0];
#pragma unroll
        for (int j = 0; j < 9; ++j) {
            g[j] = rfl(fltr[j] * inv);
            gE[j] = rfl(EGFC * g[j]);
        }
    }

    const float* img = pred + (size_t)b * (HH * WW);
    const float* snk = snake + (size_t)b * (HH * WW);
    float* g0 = out + 1 + ((size_t)(b * 2 + 0)) * (HH * WW);
    float* g1 = out + 1 + ((size_t)(b * 2 + 1)) * (HH * WW);
    float* g0W = g0 + (size_t)BB * 2 * HH * WW;
    float* g1W = g1 + (size_t)BB * 2 * HH * WW;

    // 9-deep register rings of horizontal-conv rows (statically indexed)
    float hgP[9], hdP[9], hgA[9], hdA[9];
    float svv[9];
    float4 pA, pB, pC;                 // in-flight chunk (issue-early regs)
    float lsum = 0.f;

    // ---- prologue: chunk0 (j=0..8) preload + write
    PRELOAD(0, 9);
    WRITECHUNK(9);

    // ---- warmup consume chunk0 (loss rows j=4..8); chunk1 preloads overlap
    PRELOAD(9, 9);
#pragma unroll
    for (int u = 4; u < 9; ++u)
        svv[u] = snk[(size_t)(r0 - 4 + u) * WW + c0 + lane];
#pragma unroll
    for (int u = 0; u < 9; ++u) { CROW(u, u, (u >= 4)); }
    EMIT(r0, 0);
    asm volatile("" ::: "memory");  // pin consume-reads before stage-writes
    WRITECHUNK(9);

    // ---- main: consume chunks 1..3 (jb = 9,18,27; all loss rows),
    //      preloading chunk m+2 (NR=4 for the tail chunk) under each consume
#pragma unroll 1
    for (int m = 0; m < 3; ++m) {
        const int jb = 9 + 9 * m;
        const int nrn = (m == 2) ? 4 : 9;
        PRELOAD(jb + 9, nrn);
#pragma unroll
        for (int u = 0; u < 9; ++u)
            svv[u] = snk[(size_t)(r0 - 4 + jb + u) * WW + c0 + lane];
#pragma unroll
        for (int u = 0; u < 9; ++u) {
            CROW(u, u, true);
            EMIT(r0 + jb + u - 8, (u + 1) % 9);
        }
        asm volatile("" ::: "memory");
        WRITECHUNK(nrn);
    }

    // ---- tail consume: chunk4 rows j=36..39 (below-band halo, no loss)
#pragma unroll
    for (int u = 0; u < 4; ++u) {
        CROW(u, u, false);
        EMIT(r0 + 28 + u, (u + 1) % 9);
    }

    // --- block reduction -> one atomicAdd per block
#pragma unroll
    for (int off = 32; off > 0; off >>= 1) lsum += __shfl_down(lsum, off);
    if (lane == 0) s_red[wid] = lsum;
    __syncthreads();
    if (t == 0) {
        float tot = s_red[0] + s_red[1] + s_red[2] + s_red[3];
        atomicAdd(out, tot * (1.0f / 16777216.0f));  // /(B*H*W), exact pow2
    }
}

extern "C" void kernel_launch(void* const* d_in, const int* in_sizes, int n_in,
                              void* d_out, int out_size, void* d_ws, size_t ws_size,
                              hipStream_t stream) {
    const float* pred = (const float*)d_in[0];
    const float* snake = (const float*)d_in[1];
    const float* fltr = (const float*)d_in[2];
    float* out = (float*)d_out;

    // loss accumulator must start at 0 (d_out is poisoned before every launch)
    hipMemsetAsync(out, 0, sizeof(float), stream);

    dim3 grid(WW / 256, HH / ROWS, BB);   // (4, 32, 16) = 2048 blocks
    snake_rows<<<grid, 256, 0, stream>>>(pred, snake, fltr, out);
}